// Round 1
// baseline (572.712 us; speedup 1.0000x reference)
//
#include <hip/hip_runtime.h>
#include <stdint.h>

#define N_EXPECTED 1000000
#define K_TOP 4096
#define CAP 8192            // candidate buffer (pow2, >= K_TOP + max bin count)
#define NBIN (1 << 18)      // 18-bit score histogram

// ---- workspace layout (bytes) ----
static constexpr size_t HIST_OFF = 0;                                  // NBIN * u32  = 1 MB
static constexpr size_t SCAL_OFF = (size_t)NBIN * 4;                   // 64 B scalars
static constexpr size_t CAND_OFF = SCAL_OFF + 64;                      // CAP * u64
static constexpr size_t TBOX_OFF = CAND_OFF + (size_t)CAP * 8;         // K * float4
static constexpr size_t TSC_OFF  = TBOX_OFF + (size_t)K_TOP * 16;      // K * float
static constexpr size_t MASK_OFF = TSC_OFF + (size_t)K_TOP * 4;        // K * 64 * u64 = 2 MB
static constexpr size_t KEEP_OFF = MASK_OFF + (size_t)K_TOP * 64 * 8;  // 64 * u64
static constexpr size_t PART_OFF = KEEP_OFF + 512;                     // 1024 * u32
static constexpr size_t WS_NEED  = PART_OFF + 4096;

__device__ __forceinline__ unsigned ord_of(float s) {
    unsigned u = __float_as_uint(s);
    return (u & 0x80000000u) ? ~u : (u | 0x80000000u);
}

// K1: histogram of 18-bit ordered-score prefix
__global__ void k_hist(const float* __restrict__ scores, unsigned* __restrict__ hist, int n) {
    int i = blockIdx.x * blockDim.x + threadIdx.x;
    int stride = gridDim.x * blockDim.x;
    for (; i < n; i += stride) {
        unsigned o = ord_of(scores[i]);
        atomicAdd(&hist[o >> 14], 1u);
    }
}

// K1.5: per-chunk sums (1024 chunks of 256 bins) so the scan kernel doesn't read 1MB on one CU
__global__ void k_chunksum(const unsigned* __restrict__ hist, unsigned* __restrict__ part) {
    __shared__ unsigned red[256];
    int c = blockIdx.x;
    red[threadIdx.x] = hist[c * 256 + threadIdx.x];
    __syncthreads();
    for (int off = 128; off > 0; off >>= 1) {
        if (threadIdx.x < off) red[threadIdx.x] += red[threadIdx.x + off];
        __syncthreads();
    }
    if (threadIdx.x == 0) part[c] = red[0];
}

// K2: find threshold bin T: count(bins > T) < K <= count(bins >= T)
__global__ void k_scan(const unsigned* __restrict__ hist, const unsigned* __restrict__ part,
                       unsigned* __restrict__ scal) {
    __shared__ unsigned buf[1024];
    __shared__ int s_chunk;
    __shared__ unsigned s_A;
    __shared__ unsigned buf2[256];
    __shared__ unsigned h2[256];
    int t = threadIdx.x;
    unsigned mysum = part[t];
    buf[t] = mysum;
    __syncthreads();
    // inclusive suffix scan over 1024 chunks
    for (int off = 1; off < 1024; off <<= 1) {
        unsigned v = buf[t] + ((t + off < 1024) ? buf[t + off] : 0u);
        __syncthreads();
        buf[t] = v;
        __syncthreads();
    }
    if (buf[t] >= K_TOP && (t == 1023 || buf[t + 1] < K_TOP)) {
        s_chunk = t;
        s_A = buf[t] - mysum;   // count strictly above this chunk
    }
    __syncthreads();
    int chunk = s_chunk;
    unsigned A = s_A;
    if (t < 256) { h2[t] = hist[chunk * 256 + t]; buf2[t] = h2[t]; }
    __syncthreads();
    for (int off = 1; off < 256; off <<= 1) {
        unsigned v = 0;
        if (t < 256) v = buf2[t] + ((t + off < 256) ? buf2[t + off] : 0u);
        __syncthreads();
        if (t < 256) buf2[t] = v;
        __syncthreads();
    }
    if (t < 256) {
        unsigned above = A + ((t == 255) ? 0u : buf2[t + 1]);   // count in bins > this bin
        if (above < K_TOP && A + buf2[t] >= K_TOP) {
            scal[0] = (unsigned)(chunk * 256 + t);  // T
            scal[1] = above;                        // (info only)
        }
    }
}

// K3: compact all elements with bin >= T into candidate buffer as 64-bit keys
__global__ void k_compact(const float* __restrict__ scores, const unsigned* __restrict__ scal,
                          unsigned long long* __restrict__ cand, unsigned* __restrict__ counter,
                          int n) {
    unsigned T = scal[0];
    int i = blockIdx.x * blockDim.x + threadIdx.x;
    int stride = gridDim.x * blockDim.x;
    for (; i < n; i += stride) {
        unsigned o = ord_of(scores[i]);
        if ((o >> 14) >= T) {
            unsigned pos = atomicAdd(counter, 1u);
            if (pos < CAP)
                cand[pos] = ((unsigned long long)o << 32) | (unsigned)(~i);
        }
    }
}

__device__ __forceinline__ float4 decode_clip(float4 a, float4 d) {
#pragma clang fp contract(off)
    const float BBOX_CLIP = (float)4.135166556742356;  // log(1000/16)
    float w  = a.z - a.x;
    float h  = a.w - a.y;
    float cx = a.x + 0.5f * w;
    float cy = a.y + 0.5f * h;
    float dx = d.x / 10.0f;
    float dy = d.y / 10.0f;
    float dw = fminf(d.z / 5.0f, BBOX_CLIP);
    float dh = fminf(d.w / 5.0f, BBOX_CLIP);
    float pcx = dx * w + cx;
    float pcy = dy * h + cy;
    float pw = (float)exp((double)dw) * w;
    float ph = (float)exp((double)dh) * h;
    float x1 = pcx - 0.5f * pw;
    float y1 = pcy - 0.5f * ph;
    float x2 = pcx + 0.5f * pw;
    float y2 = pcy + 0.5f * ph;
    x1 = fminf(fmaxf(x1, 0.0f), 1333.0f);
    y1 = fminf(fmaxf(y1, 0.0f), 800.0f);
    x2 = fminf(fmaxf(x2, 0.0f), 1333.0f);
    y2 = fminf(fmaxf(y2, 0.0f), 800.0f);
    return make_float4(x1, y1, x2, y2);
}

// K4: one-block bitonic sort of CAP keys (descending); decode the top K
__global__ __launch_bounds__(1024) void k_sort_gather(
        const float* __restrict__ scores, const float* __restrict__ anchors,
        const float* __restrict__ deltas, const unsigned long long* __restrict__ cand,
        const unsigned* __restrict__ scal, float4* __restrict__ tbox, float* __restrict__ tsc) {
    __shared__ unsigned long long s[CAP];
    int t = threadIdx.x;
    unsigned M = scal[2];
    if (M > CAP) M = CAP;
    for (int j = t; j < CAP; j += 1024) s[j] = (j < (int)M) ? cand[j] : 0ULL;
    __syncthreads();
    for (int k = 2; k <= CAP; k <<= 1) {
        for (int j = k >> 1; j > 0; j >>= 1) {
            for (int i = t; i < CAP; i += 1024) {
                int l = i ^ j;
                if (l > i) {
                    unsigned long long a = s[i], b = s[l];
                    bool desc = ((i & k) == 0);
                    if (desc ? (a < b) : (a > b)) { s[i] = b; s[l] = a; }
                }
            }
            __syncthreads();
        }
    }
    for (int j = t; j < K_TOP; j += 1024) {
        unsigned long long key = s[j];
        unsigned idx = ~(unsigned)key;
        float4 a = ((const float4*)anchors)[idx];
        float4 d = ((const float4*)deltas)[idx];
        tbox[j] = decode_clip(a, d);
        tsc[j]  = scores[idx];
    }
}

// K5: suppression masks. block = 64 threads (rows), grid = (colWord, rowBlock)
__global__ void k_mask(const float4* __restrict__ tbox, unsigned long long* __restrict__ mask) {
#pragma clang fp contract(off)
    int w = blockIdx.x;  // column word (64 cols)
    int r = blockIdx.y;  // row block
    int t = threadIdx.x;
    int i = r * 64 + t;
    if (w < r) { mask[(size_t)i * 64 + w] = 0ULL; return; }
    __shared__ float4 cb[64];
    __shared__ float  ca[64];
    float4 b = tbox[w * 64 + t];
    cb[t] = b;
    ca[t] = (b.z - b.x) * (b.w - b.y);
    __syncthreads();
    float4 bi = tbox[i];
    float ai = (bi.z - bi.x) * (bi.w - bi.y);
    unsigned long long bits = 0ULL;
    for (int c = 0; c < 64; ++c) {
        int j = w * 64 + c;
        if (j > i) {
            float4 bj = cb[c];
            float ltx = fmaxf(bi.x, bj.x);
            float lty = fmaxf(bi.y, bj.y);
            float rbx = fminf(bi.z, bj.z);
            float rby = fminf(bi.w, bj.w);
            float ww = fmaxf(rbx - ltx, 0.0f);
            float hh = fmaxf(rby - lty, 0.0f);
            float inter = ww * hh;
            float denom = ((ai + ca[c]) - inter) + 1e-9f;
            float iou = inter / denom;
            if (iou > 0.7f) bits |= (1ULL << c);
        }
    }
    mask[(size_t)i * 64 + w] = bits;
}

// K6: sequential greedy reduce, single wave; readlane broadcast of the keep bit
__global__ __launch_bounds__(64, 1) void k_nms(const unsigned long long* __restrict__ mask,
                                               unsigned long long* __restrict__ keep) {
    int lane = threadIdx.x;  // 0..63, owns column word `lane`
    unsigned long long remv = 0ULL;
    unsigned long long cur[32], nxt[32];
#pragma unroll
    for (int q = 0; q < 32; ++q) cur[q] = mask[(size_t)q * 64 + lane];
    for (int blk = 0; blk < 128; ++blk) {
        if (blk + 1 < 128) {
#pragma unroll
            for (int q = 0; q < 32; ++q)
                nxt[q] = mask[((size_t)(blk + 1) * 32 + q) * 64 + lane];
        }
        int word0 = blk >> 1;
#pragma unroll
        for (int q = 0; q < 32; ++q) {
            int i = blk * 32 + q;
            int bit = i & 63;
            unsigned lo = (unsigned)__builtin_amdgcn_readlane((int)(unsigned)(remv & 0xffffffffULL), word0);
            unsigned hi = (unsigned)__builtin_amdgcn_readlane((int)(unsigned)(remv >> 32), word0);
            unsigned long long rw = ((unsigned long long)hi << 32) | lo;
            if (!((rw >> bit) & 1ULL)) remv |= cur[q];
        }
        if (blk + 1 < 128) {
#pragma unroll
            for (int q = 0; q < 32; ++q) cur[q] = nxt[q];
        }
    }
    keep[lane] = ~remv;
}

// K7: write [K,5] output
__global__ void k_out(const float4* __restrict__ tbox, const float* __restrict__ tsc,
                      const unsigned long long* __restrict__ keep, float* __restrict__ out) {
    int j = blockIdx.x * blockDim.x + threadIdx.x;
    if (j >= K_TOP) return;
    bool kp = (keep[j >> 6] >> (j & 63)) & 1ULL;
    float4 b = tbox[j];
    float sc = tsc[j];
    float* o = out + (size_t)j * 5;
    o[0] = kp ? b.x : 0.0f;
    o[1] = kp ? b.y : 0.0f;
    o[2] = kp ? b.z : 0.0f;
    o[3] = kp ? b.w : 0.0f;
    o[4] = kp ? sc  : 0.0f;
}

extern "C" void kernel_launch(void* const* d_in, const int* in_sizes, int n_in,
                              void* d_out, int out_size, void* d_ws, size_t ws_size,
                              hipStream_t stream) {
    if (ws_size < WS_NEED) return;  // fail loudly (output stays poisoned)
    const float* scores  = (const float*)d_in[0];
    const float* anchors = (const float*)d_in[1];
    const float* deltas  = (const float*)d_in[2];
    int n = in_sizes[0];

    char* ws = (char*)d_ws;
    unsigned* hist            = (unsigned*)(ws + HIST_OFF);
    unsigned* scal            = (unsigned*)(ws + SCAL_OFF);
    unsigned long long* cand  = (unsigned long long*)(ws + CAND_OFF);
    float4* tbox              = (float4*)(ws + TBOX_OFF);
    float* tsc                = (float*)(ws + TSC_OFF);
    unsigned long long* mask  = (unsigned long long*)(ws + MASK_OFF);
    unsigned long long* keep  = (unsigned long long*)(ws + KEEP_OFF);
    unsigned* part            = (unsigned*)(ws + PART_OFF);

    hipMemsetAsync(ws, 0, SCAL_OFF + 64, stream);  // hist + scalars/counter
    k_hist<<<1024, 256, 0, stream>>>(scores, hist, n);
    k_chunksum<<<1024, 256, 0, stream>>>(hist, part);
    k_scan<<<1, 1024, 0, stream>>>(hist, part, scal);
    k_compact<<<1024, 256, 0, stream>>>(scores, scal, cand, &scal[2], n);
    k_sort_gather<<<1, 1024, 0, stream>>>(scores, anchors, deltas, cand, scal, tbox, tsc);
    k_mask<<<dim3(64, 64), 64, 0, stream>>>(tbox, mask);
    k_nms<<<1, 64, 0, stream>>>(mask, keep);
    k_out<<<16, 256, 0, stream>>>(tbox, tsc, keep, (float*)d_out);
}

// Round 2
// 273.645 us; speedup vs baseline: 2.0929x; 2.0929x over previous
//
#include <hip/hip_runtime.h>
#include <stdint.h>

#define K_TOP 4096
#define CAP 8192            // candidate buffer (pow2, >= K_TOP + ties margin)

// ---- workspace layout (bytes) ----
static constexpr size_t HIST1_OFF = 0;                                   // 4096 u32 = 16 KB
static constexpr size_t HIST2_OFF = 16384;                               // 4096 u32 = 16 KB
static constexpr size_t SCAL_OFF  = 32768;                               // 64 B scalars
static constexpr size_t CAND_OFF  = 32832;                               // CAP u64 = 64 KB
static constexpr size_t TBOX_OFF  = CAND_OFF + (size_t)CAP * 8;          // K float4 = 64 KB
static constexpr size_t TSC_OFF   = TBOX_OFF + (size_t)K_TOP * 16;       // K float = 16 KB
static constexpr size_t MASK_OFF  = TSC_OFF + (size_t)K_TOP * 4;         // K*64 u64 = 2 MB
static constexpr size_t KEEP_OFF  = MASK_OFF + (size_t)K_TOP * 64 * 8;   // 64 u64
static constexpr size_t WS_NEED   = KEEP_OFF + 512;

// scal slots: [0]=B1 [1]=A1(count above B1) [4]=T24 threshold [5]=compact counter

__device__ __forceinline__ unsigned ord_of(float s) {
    unsigned u = __float_as_uint(s);
    return (u & 0x80000000u) ? ~u : (u | 0x80000000u);
}

// P1: 12-bit histogram (bits 31..20 of ordered score), LDS-privatized, sparse atomic merge
__global__ void k_hist1(const float* __restrict__ scores, unsigned* __restrict__ hist, int n) {
    __shared__ unsigned h[4096];
    for (int j = threadIdx.x; j < 4096; j += 256) h[j] = 0;
    __syncthreads();
    int i = blockIdx.x * blockDim.x + threadIdx.x;
    int stride = gridDim.x * blockDim.x;
    for (; i < n; i += stride) {
        unsigned o = ord_of(scores[i]);
        atomicAdd(&h[o >> 20], 1u);
    }
    __syncthreads();
    for (int j = threadIdx.x; j < 4096; j += 256) {
        unsigned v = h[j];
        if (v) atomicAdd(&hist[j], v);
    }
}

// P2: 12-bit histogram of bits 19..8 among elements whose top-12 == B1
__global__ void k_hist2(const float* __restrict__ scores, const unsigned* __restrict__ scal,
                        unsigned* __restrict__ hist, int n) {
    __shared__ unsigned h[4096];
    for (int j = threadIdx.x; j < 4096; j += 256) h[j] = 0;
    __syncthreads();
    unsigned B1 = scal[0];
    int i = blockIdx.x * blockDim.x + threadIdx.x;
    int stride = gridDim.x * blockDim.x;
    for (; i < n; i += stride) {
        unsigned o = ord_of(scores[i]);
        if ((o >> 20) == B1) atomicAdd(&h[(o >> 8) & 4095u], 1u);
    }
    __syncthreads();
    for (int j = threadIdx.x; j < 4096; j += 256) {
        unsigned v = h[j];
        if (v) atomicAdd(&hist[j], v);
    }
}

// select threshold bin from a 4096-bin histogram via suffix scan
__global__ __launch_bounds__(1024) void k_select(const unsigned* __restrict__ hist,
                                                 unsigned* __restrict__ scal, int pass) {
    __shared__ unsigned buf[1024];
    int t = threadIdx.x;
    unsigned c0 = hist[t * 4 + 0], c1 = hist[t * 4 + 1];
    unsigned c2 = hist[t * 4 + 2], c3 = hist[t * 4 + 3];
    unsigned mysum = c0 + c1 + c2 + c3;
    buf[t] = mysum;
    __syncthreads();
    for (int off = 1; off < 1024; off <<= 1) {
        unsigned v = buf[t] + ((t + off < 1024) ? buf[t + off] : 0u);
        __syncthreads();
        buf[t] = v;
        __syncthreads();
    }
    unsigned target = (pass == 0) ? (unsigned)K_TOP : ((unsigned)K_TOP - scal[1]);
    unsigned sfx = buf[t];
    unsigned nxt = (t < 1023) ? buf[t + 1] : 0u;
    if (sfx >= target && nxt < target) {
        unsigned above = nxt;  // count in bins strictly above this 4-bin group
        unsigned b;
        if (above + c3 >= target)                { b = t * 4 + 3; }
        else if (above + c3 + c2 >= target)      { above += c3;           b = t * 4 + 2; }
        else if (above + c3 + c2 + c1 >= target) { above += c3 + c2;      b = t * 4 + 1; }
        else                                     { above += c3 + c2 + c1; b = t * 4 + 0; }
        if (pass == 0) { scal[0] = b; scal[1] = above; }
        else           { scal[4] = (scal[0] << 12) | b; }
    }
}

// compact all elements with 24-bit prefix >= T24, block-aggregated
__global__ __launch_bounds__(256) void k_compact(const float* __restrict__ scores,
                                                 const unsigned* __restrict__ scal,
                                                 unsigned long long* __restrict__ cand,
                                                 unsigned* __restrict__ counter, int n) {
    __shared__ unsigned lcount, lbase;
    __shared__ unsigned long long lbuf[4096];
    if (threadIdx.x == 0) lcount = 0;
    __syncthreads();
    unsigned T = scal[4];
    int i = blockIdx.x * blockDim.x + threadIdx.x;
    int stride = gridDim.x * blockDim.x;
    for (; i < n; i += stride) {
        unsigned o = ord_of(scores[i]);
        if ((o >> 8) >= T) {
            unsigned p = atomicAdd(&lcount, 1u);
            lbuf[p] = ((unsigned long long)o << 32) | (unsigned)(~i);
        }
    }
    __syncthreads();
    if (threadIdx.x == 0) lbase = atomicAdd(counter, lcount);
    __syncthreads();
    for (unsigned j = threadIdx.x; j < lcount; j += 256) {
        unsigned p = lbase + j;
        if (p < CAP) cand[p] = lbuf[j];
    }
}

__device__ __forceinline__ float4 decode_clip(float4 a, float4 d) {
#pragma clang fp contract(off)
    const float BBOX_CLIP = (float)4.135166556742356;  // log(1000/16)
    float w  = a.z - a.x;
    float h  = a.w - a.y;
    float cx = a.x + 0.5f * w;
    float cy = a.y + 0.5f * h;
    float dx = d.x / 10.0f;
    float dy = d.y / 10.0f;
    float dw = fminf(d.z / 5.0f, BBOX_CLIP);
    float dh = fminf(d.w / 5.0f, BBOX_CLIP);
    float pcx = dx * w + cx;
    float pcy = dy * h + cy;
    float pw = (float)exp((double)dw) * w;
    float ph = (float)exp((double)dh) * h;
    float x1 = pcx - 0.5f * pw;
    float y1 = pcy - 0.5f * ph;
    float x2 = pcx + 0.5f * pw;
    float y2 = pcy + 0.5f * ph;
    x1 = fminf(fmaxf(x1, 0.0f), 1333.0f);
    y1 = fminf(fmaxf(y1, 0.0f), 800.0f);
    x2 = fminf(fmaxf(x2, 0.0f), 1333.0f);
    y2 = fminf(fmaxf(y2, 0.0f), 800.0f);
    return make_float4(x1, y1, x2, y2);
}

// rank-by-counting over candidates; decode straight into rank slot.
// keys are unique (index in low bits) -> ranks are a permutation of 0..M-1.
__global__ __launch_bounds__(256) void k_rank_gather(
        const float* __restrict__ scores, const float* __restrict__ anchors,
        const float* __restrict__ deltas, const unsigned long long* __restrict__ cand,
        const unsigned* __restrict__ scal, float4* __restrict__ tbox, float* __restrict__ tsc) {
    __shared__ unsigned long long chunk[256];
    int t = threadIdx.x;
    int j = blockIdx.x * 256 + t;
    unsigned M = scal[5];
    if (M > CAP) M = CAP;
    unsigned long long mykey = (j < (int)M) ? cand[j] : 0ULL;
    unsigned rank = 0;
    for (unsigned base = 0; base < M; base += 256) {
        unsigned idx = base + t;
        chunk[t] = (idx < M) ? cand[idx] : 0ULL;  // pad 0 < any valid key
        __syncthreads();
#pragma unroll 8
        for (int c = 0; c < 256; ++c) rank += (chunk[c] > mykey);
        __syncthreads();
    }
    if (j < (int)M && rank < K_TOP) {
        unsigned idx = ~(unsigned)mykey;
        float4 a = ((const float4*)anchors)[idx];
        float4 d = ((const float4*)deltas)[idx];
        tbox[rank] = decode_clip(a, d);
        tsc[rank]  = scores[idx];
    }
}

// suppression masks. block = 64 threads (rows), grid = (colWord, rowBlock)
__global__ void k_mask(const float4* __restrict__ tbox, unsigned long long* __restrict__ mask) {
#pragma clang fp contract(off)
    int w = blockIdx.x;  // column word (64 cols)
    int r = blockIdx.y;  // row block
    int t = threadIdx.x;
    int i = r * 64 + t;
    if (w < r) { mask[(size_t)i * 64 + w] = 0ULL; return; }
    __shared__ float4 cb[64];
    __shared__ float  ca[64];
    float4 b = tbox[w * 64 + t];
    cb[t] = b;
    ca[t] = (b.z - b.x) * (b.w - b.y);
    __syncthreads();
    float4 bi = tbox[i];
    float ai = (bi.z - bi.x) * (bi.w - bi.y);
    unsigned long long bits = 0ULL;
    for (int c = 0; c < 64; ++c) {
        int j = w * 64 + c;
        if (j > i) {
            float4 bj = cb[c];
            float ltx = fmaxf(bi.x, bj.x);
            float lty = fmaxf(bi.y, bj.y);
            float rbx = fminf(bi.z, bj.z);
            float rby = fminf(bi.w, bj.w);
            float ww = fmaxf(rbx - ltx, 0.0f);
            float hh = fmaxf(rby - lty, 0.0f);
            float inter = ww * hh;
            float denom = ((ai + ca[c]) - inter) + 1e-9f;
            float iou = inter / denom;
            if (iou > 0.7f) bits |= (1ULL << c);
        }
    }
    mask[(size_t)i * 64 + w] = bits;
}

// sequential greedy reduce, single wave; readlane broadcast of the keep word
__global__ __launch_bounds__(64, 1) void k_nms(const unsigned long long* __restrict__ mask,
                                               unsigned long long* __restrict__ keep) {
    int lane = threadIdx.x;  // owns column word `lane`
    unsigned long long remv = 0ULL;
    unsigned long long cur[32], nxt[32];
#pragma unroll
    for (int q = 0; q < 32; ++q) cur[q] = mask[(size_t)q * 64 + lane];
    for (int blk = 0; blk < 128; ++blk) {
        if (blk + 1 < 128) {
#pragma unroll
            for (int q = 0; q < 32; ++q)
                nxt[q] = mask[((size_t)(blk + 1) * 32 + q) * 64 + lane];
        }
        int word0 = blk >> 1;
#pragma unroll
        for (int q = 0; q < 32; ++q) {
            int i = blk * 32 + q;
            int bit = i & 63;
            unsigned lo = (unsigned)__builtin_amdgcn_readlane((int)(unsigned)(remv & 0xffffffffULL), word0);
            unsigned hi = (unsigned)__builtin_amdgcn_readlane((int)(unsigned)(remv >> 32), word0);
            unsigned long long rw = ((unsigned long long)hi << 32) | lo;
            if (!((rw >> bit) & 1ULL)) remv |= cur[q];
        }
        if (blk + 1 < 128) {
#pragma unroll
            for (int q = 0; q < 32; ++q) cur[q] = nxt[q];
        }
    }
    keep[lane] = ~remv;
}

// write [K,5] output
__global__ void k_out(const float4* __restrict__ tbox, const float* __restrict__ tsc,
                      const unsigned long long* __restrict__ keep, float* __restrict__ out) {
    int j = blockIdx.x * blockDim.x + threadIdx.x;
    if (j >= K_TOP) return;
    bool kp = (keep[j >> 6] >> (j & 63)) & 1ULL;
    float4 b = tbox[j];
    float sc = tsc[j];
    float* o = out + (size_t)j * 5;
    o[0] = kp ? b.x : 0.0f;
    o[1] = kp ? b.y : 0.0f;
    o[2] = kp ? b.z : 0.0f;
    o[3] = kp ? b.w : 0.0f;
    o[4] = kp ? sc  : 0.0f;
}

extern "C" void kernel_launch(void* const* d_in, const int* in_sizes, int n_in,
                              void* d_out, int out_size, void* d_ws, size_t ws_size,
                              hipStream_t stream) {
    if (ws_size < WS_NEED) return;  // fail loudly (output stays poisoned)
    const float* scores  = (const float*)d_in[0];
    const float* anchors = (const float*)d_in[1];
    const float* deltas  = (const float*)d_in[2];
    int n = in_sizes[0];

    char* ws = (char*)d_ws;
    unsigned* hist1           = (unsigned*)(ws + HIST1_OFF);
    unsigned* hist2           = (unsigned*)(ws + HIST2_OFF);
    unsigned* scal            = (unsigned*)(ws + SCAL_OFF);
    unsigned long long* cand  = (unsigned long long*)(ws + CAND_OFF);
    float4* tbox              = (float4*)(ws + TBOX_OFF);
    float* tsc                = (float*)(ws + TSC_OFF);
    unsigned long long* mask  = (unsigned long long*)(ws + MASK_OFF);
    unsigned long long* keep  = (unsigned long long*)(ws + KEEP_OFF);

    hipMemsetAsync(ws, 0, SCAL_OFF + 64, stream);  // hist1 + hist2 + scalars

    k_hist1<<<256, 256, 0, stream>>>(scores, hist1, n);
    k_select<<<1, 1024, 0, stream>>>(hist1, scal, 0);
    k_hist2<<<256, 256, 0, stream>>>(scores, scal, hist2, n);
    k_select<<<1, 1024, 0, stream>>>(hist2, scal, 1);
    k_compact<<<256, 256, 0, stream>>>(scores, scal, cand, &scal[5], n);
    k_rank_gather<<<CAP / 256, 256, 0, stream>>>(scores, anchors, deltas, cand, scal, tbox, tsc);
    k_mask<<<dim3(64, 64), 64, 0, stream>>>(tbox, mask);
    k_nms<<<1, 64, 0, stream>>>(mask, keep);
    k_out<<<16, 256, 0, stream>>>(tbox, tsc, keep, (float*)d_out);
}